// Round 5
// baseline (810.257 us; speedup 1.0000x reference)
//
#include <hip/hip_runtime.h>

// Pipeline: conv3x3(64->128)+ReLU -> conv3x3(128->32)+ReLU -> bilinear x2 -> conv3x3(32->1)
// N=48, H=W=128 input, out [48,1,256,256] fp32.
//
// Round 9: conv1 restructured as a chunked 2-phase pipeline (stage(q+1) under MFMA(q)).
//  History: R6 weight-prefetch neutral; R7 small-tile -42% (per-block fixed cost);
//  R8 load-all-then-write +5%. Conclusion: the stall is the monolithic
//  stage->barrier->compute->drain structure (waves idle ~80% at 2 blocks/CU).
//  Now: ci split in 2 halves (chunk = 10x34 px x 32ci, 24.5KB, pitch 36 -> 2-way banks),
//  double-buffered LDS (49KB), 2 y-tiles per block (grid (4,8,48) = 3 exact waves of
//  512 resident blocks). Per chunk: {ds_write regs->lds[buf]; barrier; issue loads(q+1);
//  144 MFMA}. Loads issued AFTER the barrier so its vmcnt(0) drain never waits on the
//  prefetch; latency hides under MFMA. One barrier/chunk.
//  NOTE: K-order now (half, tap, kc) -> fp32 accum reorder, not bit-identical (tol ok).
//  - upsample fused into conv3 (R6, verified -88us). conv2 / conv3 / repacks unchanged.
// Workspace: [A: xh 96MB][B: y1h 192MB][C: y2h 48MB][W].

typedef _Float16 half_t;
typedef _Float16 half2_t __attribute__((ext_vector_type(2)));
typedef _Float16 half4_t __attribute__((ext_vector_type(4)));
typedef _Float16 half8   __attribute__((ext_vector_type(8)));
typedef float    floatx4  __attribute__((ext_vector_type(4)));
typedef float    floatx16 __attribute__((ext_vector_type(16)));

// ---------- pre-pass: weights fp32 [co][ci][3][3] -> fp16 [tap][co][ci] ----------
__global__ __launch_bounds__(256) void repack_w(
    const float* __restrict__ W1, const float* __restrict__ W2,
    const float* __restrict__ W3, half_t* __restrict__ wh1,
    half_t* __restrict__ wh2, half_t* __restrict__ wh3)
{
    int idx = blockIdx.x * 256 + threadIdx.x;
    if (idx < 73728) {                       // wh1[tap][128][64]
        int ci = idx & 63, co = (idx >> 6) & 127, tap = idx >> 13;
        wh1[idx] = (half_t)W1[(co * 64 + ci) * 9 + tap];
    } else if (idx < 110592) {               // wh2[tap][32][128]
        int j = idx - 73728;
        int ci = j & 127, co = (j >> 7) & 31, tap = j >> 12;
        wh2[j] = (half_t)W2[(co * 128 + ci) * 9 + tap];
    } else if (idx < 110880) {               // wh3[tap][32]
        int j = idx - 110592;
        int ci = j & 31, tap = j >> 5;
        wh3[j] = (half_t)W3[ci * 9 + tap];
    }
}

// ---------- pre-pass: x fp32 [48][64][128][128] -> xh fp16 NHWC [48][128][128][64] ----------
__global__ __launch_bounds__(256) void repack_x(
    const float* __restrict__ x, half_t* __restrict__ xh)
{
    const int tid = threadIdx.x;
    const int px = tid & 127, rr = tid >> 7;
    const int y = blockIdx.x * 2 + rr;
    const int n = blockIdx.y;
    const float* xn = x + (size_t)n * 64 * 16384 + (size_t)y * 128 + px;
    half2_t hb[32];
#pragma unroll
    for (int c2 = 0; c2 < 32; ++c2) {
        float f0 = xn[(size_t)(2 * c2) * 16384];
        float f1 = xn[(size_t)(2 * c2 + 1) * 16384];
        half2_t h; h.x = (half_t)f0; h.y = (half_t)f1;
        hb[c2] = h;
    }
    half_t* op = xh + (((size_t)n * 128 + y) * 128 + px) * 64;
#pragma unroll
    for (int k = 0; k < 8; ++k)
        *(half8*)(op + k * 8) = *(half8*)(&hb[k * 4]);
}

// ---------- conv1: 64->128, relu, 32x32x16 MFMA, 2-phase chunk pipeline ----------
// grid (4, 8, 48). block = 128co x (32w x 8h), 2 y-tiles/block, ci in 2 halves.
// 4 waves = (wco 0..1) x (wpx 0..1); wave = 64co x (32w x 4h), acc[2][4] (128 AGPR).
// chunk = 10x34 px x 32 ci (pitch 36 halfs -> 2-way banks = free), dbuf 49KB.
__global__ __launch_bounds__(256, 2) void conv1_mfma(
    const half_t* __restrict__ xh,   // [n][128][128][64]
    const half_t* __restrict__ wh,   // [9][128][64]
    const float*  __restrict__ bias, // [128]
    half_t* __restrict__ y1h)        // [n][128][128][128]
{
    __shared__ half_t lx[2][10 * 34 * 36];   // 2 x 24480 B
    const int tid  = threadIdx.x;
    const int lane = tid & 63;
    const int wave = tid >> 6;
    const int l31 = lane & 31, lq = lane >> 5;
    const int wco = wave >> 1, wpx = wave & 1;
    const int x0 = blockIdx.x * 32;
    const int ybase = blockIdx.y * 16;
    const int n = blockIdx.z;
    const half_t* xn = xh + (size_t)n * (128 * 128 * 64);

    // staging regs: 1360 half8 per chunk (10x34 px x 4), 6 per thread guarded.
    half8 st[6];

    // prologue: load chunk 0 (tile 0, ci half 0)
#pragma unroll
    for (int k = 0; k < 6; ++k) {
        int idx = tid + k * 256;
        half8 v = {};
        if (idx < 1360) {
            int ch = idx & 3;
            int p  = idx >> 2;
            int col = p % 34, row = p / 34;
            int gx = x0 - 1 + col, gy = ybase - 1 + row;
            if ((unsigned)gx < 128u && (unsigned)gy < 128u)
                v = *(const half8*)(xn + ((size_t)gy * 128 + gx) * 64 + ch * 8);
        }
        st[k] = v;
    }

#pragma unroll
    for (int t = 0; t < 2; ++t) {
        const int y0 = ybase + t * 8;
        floatx16 acc[2][4] = {};
#pragma unroll
        for (int h = 0; h < 2; ++h) {
            const int q = t * 2 + h;
            const int buf = q & 1;

            // phase A: write staged regs -> lds[buf] (waits the in-flight loads)
#pragma unroll
            for (int k = 0; k < 6; ++k) {
                int idx = tid + k * 256;
                if (idx < 1360) {
                    int ch = idx & 3;
                    int p  = idx >> 2;
                    int col = p % 34, row = p / 34;
                    *(half8*)(&lx[buf][(row * 34 + col) * 36 + ch * 8]) = st[k];
                }
            }
            __syncthreads();   // vmcnt clean here: st already consumed -> no prefetch drained

            // phase B: issue next chunk's loads (latency hides under this chunk's MFMAs)
            if (q < 3) {
                const int tn = (q + 1) >> 1, hn = (q + 1) & 1;
                const int y0n = ybase + tn * 8;
#pragma unroll
                for (int k = 0; k < 6; ++k) {
                    int idx = tid + k * 256;
                    half8 v = {};
                    if (idx < 1360) {
                        int ch = idx & 3;
                        int p  = idx >> 2;
                        int col = p % 34, row = p / 34;
                        int gx = x0 - 1 + col, gy = y0n - 1 + row;
                        if ((unsigned)gx < 128u && (unsigned)gy < 128u)
                            v = *(const half8*)(xn + ((size_t)gy * 128 + gx) * 64 + hn * 32 + ch * 8);
                    }
                    st[k] = v;
                }
            }

            // phase C: compute chunk q (9 taps x 2 kc x 8 MFMA = 144)
#pragma unroll
            for (int tap = 0; tap < 9; ++tap) {
                const int dy = tap / 3, dx = tap % 3;
                // A: lane holds W[co = wco*64 + mf*32 + l31][ci = h*32 + kc*16 + lq*8 + j]
                const half_t* wt = wh + tap * (128 * 64) + (wco * 64 + l31) * 64 + h * 32 + lq * 8;
                // B: lane holds X[ci][px]; wave rows wpx*4+nf, col l31 (+halo shift dx,dy)
                const half_t* bp = &lx[buf][((wpx * 4 + dy) * 34 + l31 + dx) * 36 + lq * 8];
#pragma unroll
                for (int kc = 0; kc < 2; ++kc) {
                    half8 a0 = *(const half8*)(wt + kc * 16);
                    half8 a1 = *(const half8*)(wt + 32 * 64 + kc * 16);
                    half8 b[4];
#pragma unroll
                    for (int nf = 0; nf < 4; ++nf)
                        b[nf] = *(const half8*)(bp + nf * (34 * 36) + kc * 16);
#pragma unroll
                    for (int nf = 0; nf < 4; ++nf) {
                        acc[0][nf] = __builtin_amdgcn_mfma_f32_32x32x16_f16(a0, b[nf], acc[0][nf], 0, 0, 0);
                        acc[1][nf] = __builtin_amdgcn_mfma_f32_32x32x16_f16(a1, b[nf], acc[1][nf], 0, 0, 0);
                    }
                }
            }
        }

        // writeout tile t. C/D 32x32: col(px)=l31, row(co local)=(reg&3)+8*(reg>>2)+4*lq
#pragma unroll
        for (int mf = 0; mf < 2; ++mf) {
            int co0 = wco * 64 + mf * 32 + lq * 4;
#pragma unroll
            for (int nf = 0; nf < 4; ++nf) {
                floatx16 A = acc[mf][nf];
                int oy = y0 + wpx * 4 + nf, ox = x0 + l31;
                half_t* op = y1h + (((size_t)n * 128 + oy) * 128 + ox) * 128 + co0;
#pragma unroll
                for (int g = 0; g < 4; ++g) {
                    floatx4 bv = *(const floatx4*)(bias + co0 + 8 * g);
                    half4_t o;
                    o.x = (half_t)fmaxf(A[4 * g + 0] + bv.x, 0.f);
                    o.y = (half_t)fmaxf(A[4 * g + 1] + bv.y, 0.f);
                    o.z = (half_t)fmaxf(A[4 * g + 2] + bv.z, 0.f);
                    o.w = (half_t)fmaxf(A[4 * g + 3] + bv.w, 0.f);
                    *(half4_t*)(op + 8 * g) = o;
                }
            }
        }
    }
}

// ---------- conv2: 128->32, relu, 16x16x32 MFMA ----------
// grid (4, 8, 48). block = 32co x (32w x 16h px). 4 waves = 4 row-quads.
// ci staged in quarters of 32 (LDS 49KB). wave = 32co x 128px:
// acc[2][8] floatx4 (64 AGPR), 16 MFMA per {2 global A + 8 LDS B} loads.
__global__ __launch_bounds__(256, 3) void conv2_mfma(
    const half_t* __restrict__ y1h,  // [n][128][128][128]
    const half_t* __restrict__ wh,   // [9][32][128]
    const float*  __restrict__ bias, // [32]
    half_t* __restrict__ y2h)        // [n][128][128][32]
{
    __shared__ half_t lx[18 * 34 * 40];   // rows(16+2) x cols(32+2) x ci(32 pad 40)
    const int tid  = threadIdx.x;
    const int lane = tid & 63;
    const int w    = tid >> 6;
    const int l15 = lane & 15, quad = lane >> 4;
    const int x0 = blockIdx.x * 32, y0 = blockIdx.y * 16;
    const int n = blockIdx.z;
    const half_t* yn = y1h + (size_t)n * (128 * 128 * 128);

    floatx4 acc[2][8] = {};

    for (int h = 0; h < 4; ++h) {        // ci quarters of 32
        for (int idx = tid; idx < 18 * 34 * 4; idx += 256) {
            int ch = idx & 3;
            int col = (idx >> 2) % 34;
            int row = (idx >> 2) / 34;
            int gx = x0 - 1 + col, gy = y0 - 1 + row;
            half8 v = {};
            if ((unsigned)gx < 128u && (unsigned)gy < 128u)
                v = *(const half8*)(yn + ((size_t)gy * 128 + gx) * 128 + h * 32 + ch * 8);
            *(half8*)(&lx[(row * 34 + col) * 40 + ch * 8]) = v;
        }
        __syncthreads();
#pragma unroll
        for (int tap = 0; tap < 9; ++tap) {
            const int dy = tap / 3, dx = tap % 3;
            // A: co = mf*16 + l15, k = h*32 + quad*8 + j
            const half_t* wt = wh + tap * (32 * 128) + l15 * 128 + h * 32 + quad * 8;
            half8 a0 = *(const half8*)(wt);
            half8 a1 = *(const half8*)(wt + 16 * 128);
#pragma unroll
            for (int nf = 0; nf < 8; ++nf) {
                int rr = w * 4 + (nf >> 1) + dy;          // row in lx
                int cc = (nf & 1) * 16 + l15 + dx;        // col in lx
                half8 b = *(const half8*)(&lx[(rr * 34 + cc) * 40 + quad * 8]);
                acc[0][nf] = __builtin_amdgcn_mfma_f32_16x16x32_f16(a0, b, acc[0][nf], 0, 0, 0);
                acc[1][nf] = __builtin_amdgcn_mfma_f32_16x16x32_f16(a1, b, acc[1][nf], 0, 0, 0);
            }
        }
        __syncthreads();
    }

    // C/D 16x16: col(px)=l15, row(co local)=quad*4+reg
#pragma unroll
    for (int mf = 0; mf < 2; ++mf) {
        int co0 = mf * 16 + quad * 4;
        floatx4 bv = *(const floatx4*)(bias + co0);
#pragma unroll
        for (int nf = 0; nf < 8; ++nf) {
            int oy = y0 + w * 4 + (nf >> 1), ox = x0 + (nf & 1) * 16 + l15;
            floatx4 A = acc[mf][nf];
            half4_t o;
            o.x = (half_t)fmaxf(A.x + bv.x, 0.f);
            o.y = (half_t)fmaxf(A.y + bv.y, 0.f);
            o.z = (half_t)fmaxf(A.z + bv.z, 0.f);
            o.w = (half_t)fmaxf(A.w + bv.w, 0.f);
            *(half4_t*)(y2h + (((size_t)n * 128 + oy) * 128 + ox) * 32 + co0) = o;
        }
    }
}

// ---------- conv3 fused with bilinear x2: 32->1, fp32 out ----------
// grid (8, 32, 48): block = 32w x 8h out px at 256-res, thread = 1 px.
// The 10x34x32 upsampled halo tile is built directly in LDS from y2h
// (half-pixel-center bilinear, clamp edge; zero outside image for conv pad).
__global__ __launch_bounds__(256) void conv3_fused(
    const half_t* __restrict__ y2h,  // [n][128][128][32]
    const half_t* __restrict__ wh3,  // [9][32]
    const float*  __restrict__ bias, // [1]
    float* __restrict__ out)         // [n][256][256]
{
    __shared__ half_t lu[10 * 34 * 40];   // ci pitch 32 pad 40 (bank spread)
    const int tid = threadIdx.x;
    const int c = tid & 31, r = tid >> 5;
    const int x0 = blockIdx.x * 32, y0 = blockIdx.y * 8;
    const int n = blockIdx.z;
    const half_t* base = y2h + (size_t)n * (128 * 128 * 32);

    // build upsampled tile: 340 px x 4 ci-chunks (y2h is L3-resident, 50 MB)
    for (int idx = tid; idx < 10 * 34 * 4; idx += 256) {
        int cc = idx & 3;
        int p  = idx >> 2;
        int col = p % 34, row = p / 34;
        int X = x0 - 1 + col, Y = y0 - 1 + row;
        half8 o = {};
        if ((unsigned)X < 256u && (unsigned)Y < 256u) {
            int jx = X >> 1, jy = Y >> 1;
            int jxo = (X & 1) ? (jx < 127 ? jx + 1 : 127) : (jx > 0 ? jx - 1 : 0);
            int jyo = (Y & 1) ? (jy < 127 ? jy + 1 : 127) : (jy > 0 ? jy - 1 : 0);
            const half_t* p00 = base + ((size_t)jy  * 128 + jx ) * 32 + cc * 8;
            const half_t* p01 = base + ((size_t)jy  * 128 + jxo) * 32 + cc * 8;
            const half_t* p10 = base + ((size_t)jyo * 128 + jx ) * 32 + cc * 8;
            const half_t* p11 = base + ((size_t)jyo * 128 + jxo) * 32 + cc * 8;
            half8 v00 = *(const half8*)p00;
            half8 v01 = *(const half8*)p01;
            half8 v10 = *(const half8*)p10;
            half8 v11 = *(const half8*)p11;
            o = v00 * (half_t)0.5625f + (v01 + v10) * (half_t)0.1875f
              + v11 * (half_t)0.0625f;
        }
        *(half8*)(&lu[(row * 34 + col) * 40 + cc * 8]) = o;
    }
    __syncthreads();

    float acc = 0.f;
#pragma unroll
    for (int tap = 0; tap < 9; ++tap) {
        const int dy = tap / 3, dx = tap % 3;
        const half_t* lp = &lu[((r + dy) * 34 + c + dx) * 40];
        const half_t* wp = wh3 + tap * 32;
#pragma unroll
        for (int cc = 0; cc < 4; ++cc) {
            half8 v = *(const half8*)(lp + cc * 8);
            half8 w = *(const half8*)(wp + cc * 8);
            acc = __builtin_amdgcn_fdot2(__builtin_shufflevector(v, v, 0, 1),
                                         __builtin_shufflevector(w, w, 0, 1), acc, false);
            acc = __builtin_amdgcn_fdot2(__builtin_shufflevector(v, v, 2, 3),
                                         __builtin_shufflevector(w, w, 2, 3), acc, false);
            acc = __builtin_amdgcn_fdot2(__builtin_shufflevector(v, v, 4, 5),
                                         __builtin_shufflevector(w, w, 4, 5), acc, false);
            acc = __builtin_amdgcn_fdot2(__builtin_shufflevector(v, v, 6, 7),
                                         __builtin_shufflevector(w, w, 6, 7), acc, false);
        }
    }
    out[((size_t)n * 256 + (y0 + r)) * 256 + x0 + c] = acc + bias[0];
}

extern "C" void kernel_launch(void* const* d_in, const int* in_sizes, int n_in,
                              void* d_out, int out_size, void* d_ws, size_t ws_size,
                              hipStream_t stream) {
    const float* x  = (const float*)d_in[0];
    // d_in[1] = to_process (identity arange), d_in[2] = batch_size: unused.
    const float* W1 = (const float*)d_in[3];
    const float* b1 = (const float*)d_in[4];
    const float* W2 = (const float*)d_in[5];
    const float* b2 = (const float*)d_in[6];
    const float* W3 = (const float*)d_in[7];
    const float* b3 = (const float*)d_in[8];
    float* out = (float*)d_out;

    char* ws = (char*)d_ws;
    half_t* xh  = (half_t*)ws;                   // 96 MB, region A
    half_t* y1h = (half_t*)(ws + 201326592ull);  // 192 MB, region B
    half_t* y2h = (half_t*)(ws + 402653184ull);  // 48 MB,  region C
    half_t* wh1 = (half_t*)(ws + 452984832ull);  // 9*128*64
    half_t* wh2 = wh1 + 73728;                   // 9*32*128
    half_t* wh3 = wh2 + 36864;                   // 9*32

    repack_w<<<434, 256, 0, stream>>>(W1, W2, W3, wh1, wh2, wh3);
    repack_x<<<dim3(64, 48), 256, 0, stream>>>(x, xh);
    conv1_mfma<<<dim3(4, 8, 48), 256, 0, stream>>>(xh, wh1, b1, y1h);
    conv2_mfma<<<dim3(4, 8, 48), 256, 0, stream>>>(y1h, wh2, b2, y2h);
    conv3_fused<<<dim3(8, 32, 48), 256, 0, stream>>>(y2h, wh3, b3, out);
}

// Round 6
// 771.840 us; speedup vs baseline: 1.0498x; 1.0498x over previous
//
#include <hip/hip_runtime.h>

// Pipeline: conv3x3(64->128)+ReLU -> conv3x3(128->32)+ReLU -> bilinear x2 -> conv3x3(32->1)
// N=48, H=W=128 input, out [48,1,256,256] fp32.
//
// Round 10:
//  - conv1: exact revert to R8 (194us verified). R9's chunked pipeline regressed to 267:
//    pitch-36 LDS caused 1.04M bank conflicts/dispatch (b128 spans 4 banks; 18-dword
//    stride collides lane7 with lane0) and barriers/tile doubled. Lesson: pitch 72 is
//    measured-conflict-free; don't touch verified properties while changing structure.
//  - conv2: R8's load-all-then-write applied to each ci-quarter stage (10 unrolled
//    guarded half8 loads into regs, then LDS writes). Geometry/pitch/barriers unchanged.
//  - conv3: 2x per-block work (16 out rows, LDS 18x34x40 = 49KB, grid (8,16,48)) to
//    amortize per-block stage/launch overhead (R7 lesson), + load-then-write staging.
//  conv1 total-other split: conv1 194us vs ~547us in {conv2,conv3,repack_x,repack_w}
//  (each <194 since top-5 is all conv1) -> this round targets the 547.
// Workspace: [A: xh 96MB][B: y1h 192MB][C: y2h 48MB][W].

typedef _Float16 half_t;
typedef _Float16 half2_t __attribute__((ext_vector_type(2)));
typedef _Float16 half4_t __attribute__((ext_vector_type(4)));
typedef _Float16 half8   __attribute__((ext_vector_type(8)));
typedef float    floatx4  __attribute__((ext_vector_type(4)));
typedef float    floatx16 __attribute__((ext_vector_type(16)));

// ---------- pre-pass: weights fp32 [co][ci][3][3] -> fp16 [tap][co][ci] ----------
__global__ __launch_bounds__(256) void repack_w(
    const float* __restrict__ W1, const float* __restrict__ W2,
    const float* __restrict__ W3, half_t* __restrict__ wh1,
    half_t* __restrict__ wh2, half_t* __restrict__ wh3)
{
    int idx = blockIdx.x * 256 + threadIdx.x;
    if (idx < 73728) {                       // wh1[tap][128][64]
        int ci = idx & 63, co = (idx >> 6) & 127, tap = idx >> 13;
        wh1[idx] = (half_t)W1[(co * 64 + ci) * 9 + tap];
    } else if (idx < 110592) {               // wh2[tap][32][128]
        int j = idx - 73728;
        int ci = j & 127, co = (j >> 7) & 31, tap = j >> 12;
        wh2[j] = (half_t)W2[(co * 128 + ci) * 9 + tap];
    } else if (idx < 110880) {               // wh3[tap][32]
        int j = idx - 110592;
        int ci = j & 31, tap = j >> 5;
        wh3[j] = (half_t)W3[ci * 9 + tap];
    }
}

// ---------- pre-pass: x fp32 [48][64][128][128] -> xh fp16 NHWC [48][128][128][64] ----------
__global__ __launch_bounds__(256) void repack_x(
    const float* __restrict__ x, half_t* __restrict__ xh)
{
    const int tid = threadIdx.x;
    const int px = tid & 127, rr = tid >> 7;
    const int y = blockIdx.x * 2 + rr;
    const int n = blockIdx.y;
    const float* xn = x + (size_t)n * 64 * 16384 + (size_t)y * 128 + px;
    half2_t hb[32];
#pragma unroll
    for (int c2 = 0; c2 < 32; ++c2) {
        float f0 = xn[(size_t)(2 * c2) * 16384];
        float f1 = xn[(size_t)(2 * c2 + 1) * 16384];
        half2_t h; h.x = (half_t)f0; h.y = (half_t)f1;
        hb[c2] = h;
    }
    half_t* op = xh + (((size_t)n * 128 + y) * 128 + px) * 64;
#pragma unroll
    for (int k = 0; k < 8; ++k)
        *(half8*)(op + k * 8) = *(half8*)(&hb[k * 4]);
}

// ---------- conv1: 64->128, relu, 32x32x16 MFMA (R8 verified: 194us) ----------
// grid (4, 16, 48). block = 128co x (32w x 8h). 4 waves = (wco 0..1) x (wpx 0..1).
// wave = 64co x (32w x 4h) -> acc[2][4] floatx16 (128 AGPR), 8 MFMA per 6 loads.
// Stage: load-all-then-write (11 unrolled half8 loads in flight, then LDS writes).
__global__ __launch_bounds__(256, 2) void conv1_mfma(
    const half_t* __restrict__ xh,   // [n][128][128][64]
    const half_t* __restrict__ wh,   // [9][128][64]
    const float*  __restrict__ bias, // [128]
    half_t* __restrict__ y1h)        // [n][128][128][128]
{
    __shared__ half_t lx[10 * 34 * 72];   // rows(8+2) x cols(32+2) x ci(64 pad 72)
    const int tid  = threadIdx.x;
    const int lane = tid & 63;
    const int wave = tid >> 6;
    const int l31 = lane & 31, lq = lane >> 5;
    const int wco = wave >> 1, wpx = wave & 1;
    const int x0 = blockIdx.x * 32, y0 = blockIdx.y * 8;
    const int n = blockIdx.z;
    const half_t* xn = xh + (size_t)n * (128 * 128 * 64);

    // stage x tile rows y0-1..y0+8, cols x0-1..x0+32 (zero pad at borders).
    half8 st[11];
#pragma unroll
    for (int k = 0; k < 11; ++k) {
        int idx = tid + k * 256;
        half8 v = {};
        if (idx < 10 * 34 * 8) {
            int ch = idx & 7;
            int p  = idx >> 3;
            int col = p % 34, row = p / 34;
            int gx = x0 - 1 + col, gy = y0 - 1 + row;
            if ((unsigned)gx < 128u && (unsigned)gy < 128u)
                v = *(const half8*)(xn + ((size_t)gy * 128 + gx) * 64 + ch * 8);
        }
        st[k] = v;
    }
#pragma unroll
    for (int k = 0; k < 11; ++k) {
        int idx = tid + k * 256;
        if (idx < 10 * 34 * 8) {
            int ch = idx & 7;
            int p  = idx >> 3;
            int col = p % 34, row = p / 34;
            *(half8*)(&lx[(row * 34 + col) * 72 + ch * 8]) = st[k];
        }
    }
    __syncthreads();

    floatx16 acc[2][4] = {};

#pragma unroll
    for (int tap = 0; tap < 9; ++tap) {
        const int dy = tap / 3, dx = tap % 3;   // compile-time under unroll
        // A: lane holds W[co = wco*64 + mf*32 + l31][k = kc*16 + lq*8 + j]
        const half_t* wt = wh + tap * (128 * 64) + (wco * 64 + l31) * 64 + lq * 8;
        // B: lane holds X[k][px]; wave rows wpx*4+nf, col l31 (+halo shift dx,dy)
        const half_t* bp = &lx[((wpx * 4 + dy) * 34 + l31 + dx) * 72 + lq * 8];
#pragma unroll
        for (int kc = 0; kc < 4; ++kc) {
            half8 a0 = *(const half8*)(wt + kc * 16);
            half8 a1 = *(const half8*)(wt + 32 * 64 + kc * 16);
            half8 b[4];
#pragma unroll
            for (int nf = 0; nf < 4; ++nf)
                b[nf] = *(const half8*)(bp + nf * (34 * 72) + kc * 16);
#pragma unroll
            for (int nf = 0; nf < 4; ++nf) {
                acc[0][nf] = __builtin_amdgcn_mfma_f32_32x32x16_f16(a0, b[nf], acc[0][nf], 0, 0, 0);
                acc[1][nf] = __builtin_amdgcn_mfma_f32_32x32x16_f16(a1, b[nf], acc[1][nf], 0, 0, 0);
            }
        }
    }

    // C/D 32x32: col(px) = l31, row(co local) = (reg&3) + 8*(reg>>2) + 4*lq
#pragma unroll
    for (int mf = 0; mf < 2; ++mf) {
        int co0 = wco * 64 + mf * 32 + lq * 4;
#pragma unroll
        for (int nf = 0; nf < 4; ++nf) {
            floatx16 A = acc[mf][nf];
            int oy = y0 + wpx * 4 + nf, ox = x0 + l31;
            half_t* op = y1h + (((size_t)n * 128 + oy) * 128 + ox) * 128 + co0;
#pragma unroll
            for (int g = 0; g < 4; ++g) {
                floatx4 bv = *(const floatx4*)(bias + co0 + 8 * g);
                half4_t o;
                o.x = (half_t)fmaxf(A[4 * g + 0] + bv.x, 0.f);
                o.y = (half_t)fmaxf(A[4 * g + 1] + bv.y, 0.f);
                o.z = (half_t)fmaxf(A[4 * g + 2] + bv.z, 0.f);
                o.w = (half_t)fmaxf(A[4 * g + 3] + bv.w, 0.f);
                *(half4_t*)(op + 8 * g) = o;
            }
        }
    }
}

// ---------- conv2: 128->32, relu, 16x16x32 MFMA ----------
// grid (4, 8, 48). block = 32co x (32w x 16h px). 4 waves = 4 row-quads.
// ci staged in quarters of 32 (LDS 49KB). wave = 32co x 128px:
// acc[2][8] floatx4 (64 AGPR), 16 MFMA per {2 global A + 8 LDS B} loads.
// Stage per quarter: load-all-then-write (10 unrolled guarded half8 loads).
__global__ __launch_bounds__(256, 3) void conv2_mfma(
    const half_t* __restrict__ y1h,  // [n][128][128][128]
    const half_t* __restrict__ wh,   // [9][32][128]
    const float*  __restrict__ bias, // [32]
    half_t* __restrict__ y2h)        // [n][128][128][32]
{
    __shared__ half_t lx[18 * 34 * 40];   // rows(16+2) x cols(32+2) x ci(32 pad 40)
    const int tid  = threadIdx.x;
    const int lane = tid & 63;
    const int w    = tid >> 6;
    const int l15 = lane & 15, quad = lane >> 4;
    const int x0 = blockIdx.x * 32, y0 = blockIdx.y * 16;
    const int n = blockIdx.z;
    const half_t* yn = y1h + (size_t)n * (128 * 128 * 128);

    floatx4 acc[2][8] = {};

    for (int h = 0; h < 4; ++h) {        // ci quarters of 32
        // phase 1: all loads in flight
        half8 st[10];
#pragma unroll
        for (int k = 0; k < 10; ++k) {
            int idx = tid + k * 256;
            half8 v = {};
            if (idx < 18 * 34 * 4) {
                int ch = idx & 3;
                int p  = idx >> 2;
                int col = p % 34, row = p / 34;
                int gx = x0 - 1 + col, gy = y0 - 1 + row;
                if ((unsigned)gx < 128u && (unsigned)gy < 128u)
                    v = *(const half8*)(yn + ((size_t)gy * 128 + gx) * 128 + h * 32 + ch * 8);
            }
            st[k] = v;
        }
        // phase 2: LDS writes
#pragma unroll
        for (int k = 0; k < 10; ++k) {
            int idx = tid + k * 256;
            if (idx < 18 * 34 * 4) {
                int ch = idx & 3;
                int p  = idx >> 2;
                int col = p % 34, row = p / 34;
                *(half8*)(&lx[(row * 34 + col) * 40 + ch * 8]) = st[k];
            }
        }
        __syncthreads();
#pragma unroll
        for (int tap = 0; tap < 9; ++tap) {
            const int dy = tap / 3, dx = tap % 3;
            // A: co = mf*16 + l15, k = h*32 + quad*8 + j
            const half_t* wt = wh + tap * (32 * 128) + l15 * 128 + h * 32 + quad * 8;
            half8 a0 = *(const half8*)(wt);
            half8 a1 = *(const half8*)(wt + 16 * 128);
#pragma unroll
            for (int nf = 0; nf < 8; ++nf) {
                int rr = w * 4 + (nf >> 1) + dy;          // row in lx
                int cc = (nf & 1) * 16 + l15 + dx;        // col in lx
                half8 b = *(const half8*)(&lx[(rr * 34 + cc) * 40 + quad * 8]);
                acc[0][nf] = __builtin_amdgcn_mfma_f32_16x16x32_f16(a0, b, acc[0][nf], 0, 0, 0);
                acc[1][nf] = __builtin_amdgcn_mfma_f32_16x16x32_f16(a1, b, acc[1][nf], 0, 0, 0);
            }
        }
        __syncthreads();
    }

    // C/D 16x16: col(px)=l15, row(co local)=quad*4+reg
#pragma unroll
    for (int mf = 0; mf < 2; ++mf) {
        int co0 = mf * 16 + quad * 4;
        floatx4 bv = *(const floatx4*)(bias + co0);
#pragma unroll
        for (int nf = 0; nf < 8; ++nf) {
            int oy = y0 + w * 4 + (nf >> 1), ox = x0 + (nf & 1) * 16 + l15;
            floatx4 A = acc[mf][nf];
            half4_t o;
            o.x = (half_t)fmaxf(A.x + bv.x, 0.f);
            o.y = (half_t)fmaxf(A.y + bv.y, 0.f);
            o.z = (half_t)fmaxf(A.z + bv.z, 0.f);
            o.w = (half_t)fmaxf(A.w + bv.w, 0.f);
            *(half4_t*)(y2h + (((size_t)n * 128 + oy) * 128 + ox) * 32 + co0) = o;
        }
    }
}

// ---------- conv3 fused with bilinear x2: 32->1, fp32 out ----------
// grid (8, 16, 48): block = 32w x 16h out px (2 sub-tiles), thread = 2 px.
// 18x34x32 upsampled halo tile built in LDS from y2h (bilinear, clamp edge;
// zero outside image for conv pad). 2x per-block work amortizes stage cost.
__global__ __launch_bounds__(256) void conv3_fused(
    const half_t* __restrict__ y2h,  // [n][128][128][32]
    const half_t* __restrict__ wh3,  // [9][32]
    const float*  __restrict__ bias, // [1]
    float* __restrict__ out)         // [n][256][256]
{
    __shared__ half_t lu[18 * 34 * 40];   // rows(16+2) x cols(32+2) x ci(32 pad 40)
    const int tid = threadIdx.x;
    const int c = tid & 31, r = tid >> 5;
    const int x0 = blockIdx.x * 32, y0 = blockIdx.y * 16;
    const int n = blockIdx.z;
    const half_t* base = y2h + (size_t)n * (128 * 128 * 32);

    // stage upsampled tile rows Y = y0-1 .. y0+16 (18 rows) x 34 cols x 32 ci.
    // load-then-write: blend into st regs (loads pipelined across unroll), then LDS.
    half8 st[10];
#pragma unroll
    for (int k = 0; k < 10; ++k) {
        int idx = tid + k * 256;
        half8 o = {};
        if (idx < 18 * 34 * 4) {
            int cc = idx & 3;
            int p  = idx >> 2;
            int col = p % 34, row = p / 34;
            int X = x0 - 1 + col, Y = y0 - 1 + row;
            if ((unsigned)X < 256u && (unsigned)Y < 256u) {
                int jx = X >> 1, jy = Y >> 1;
                int jxo = (X & 1) ? (jx < 127 ? jx + 1 : 127) : (jx > 0 ? jx - 1 : 0);
                int jyo = (Y & 1) ? (jy < 127 ? jy + 1 : 127) : (jy > 0 ? jy - 1 : 0);
                const half_t* p00 = base + ((size_t)jy  * 128 + jx ) * 32 + cc * 8;
                const half_t* p01 = base + ((size_t)jy  * 128 + jxo) * 32 + cc * 8;
                const half_t* p10 = base + ((size_t)jyo * 128 + jx ) * 32 + cc * 8;
                const half_t* p11 = base + ((size_t)jyo * 128 + jxo) * 32 + cc * 8;
                half8 v00 = *(const half8*)p00;
                half8 v01 = *(const half8*)p01;
                half8 v10 = *(const half8*)p10;
                half8 v11 = *(const half8*)p11;
                o = v00 * (half_t)0.5625f + (v01 + v10) * (half_t)0.1875f
                  + v11 * (half_t)0.0625f;
            }
        }
        st[k] = o;
    }
#pragma unroll
    for (int k = 0; k < 10; ++k) {
        int idx = tid + k * 256;
        if (idx < 18 * 34 * 4) {
            int cc = idx & 3;
            int p  = idx >> 2;
            int col = p % 34, row = p / 34;
            *(half8*)(&lu[(row * 34 + col) * 40 + cc * 8]) = st[k];
        }
    }
    __syncthreads();

#pragma unroll
    for (int s = 0; s < 2; ++s) {        // two 8-row sub-tiles
        float acc = 0.f;
#pragma unroll
        for (int tap = 0; tap < 9; ++tap) {
            const int dy = tap / 3, dx = tap % 3;
            const half_t* lp = &lu[((s * 8 + r + dy) * 34 + c + dx) * 40];
            const half_t* wp = wh3 + tap * 32;
#pragma unroll
            for (int cc = 0; cc < 4; ++cc) {
                half8 v = *(const half8*)(lp + cc * 8);
                half8 w = *(const half8*)(wp + cc * 8);
                acc = __builtin_amdgcn_fdot2(__builtin_shufflevector(v, v, 0, 1),
                                             __builtin_shufflevector(w, w, 0, 1), acc, false);
                acc = __builtin_amdgcn_fdot2(__builtin_shufflevector(v, v, 2, 3),
                                             __builtin_shufflevector(w, w, 2, 3), acc, false);
                acc = __builtin_amdgcn_fdot2(__builtin_shufflevector(v, v, 4, 5),
                                             __builtin_shufflevector(w, w, 4, 5), acc, false);
                acc = __builtin_amdgcn_fdot2(__builtin_shufflevector(v, v, 6, 7),
                                             __builtin_shufflevector(w, w, 6, 7), acc, false);
            }
        }
        out[((size_t)n * 256 + (y0 + s * 8 + r)) * 256 + x0 + c] = acc + bias[0];
    }
}

extern "C" void kernel_launch(void* const* d_in, const int* in_sizes, int n_in,
                              void* d_out, int out_size, void* d_ws, size_t ws_size,
                              hipStream_t stream) {
    const float* x  = (const float*)d_in[0];
    // d_in[1] = to_process (identity arange), d_in[2] = batch_size: unused.
    const float* W1 = (const float*)d_in[3];
    const float* b1 = (const float*)d_in[4];
    const float* W2 = (const float*)d_in[5];
    const float* b2 = (const float*)d_in[6];
    const float* W3 = (const float*)d_in[7];
    const float* b3 = (const float*)d_in[8];
    float* out = (float*)d_out;

    char* ws = (char*)d_ws;
    half_t* xh  = (half_t*)ws;                   // 96 MB, region A
    half_t* y1h = (half_t*)(ws + 201326592ull);  // 192 MB, region B
    half_t* y2h = (half_t*)(ws + 402653184ull);  // 48 MB,  region C
    half_t* wh1 = (half_t*)(ws + 452984832ull);  // 9*128*64
    half_t* wh2 = wh1 + 73728;                   // 9*32*128
    half_t* wh3 = wh2 + 36864;                   // 9*32

    repack_w<<<434, 256, 0, stream>>>(W1, W2, W3, wh1, wh2, wh3);
    repack_x<<<dim3(64, 48), 256, 0, stream>>>(x, xh);
    conv1_mfma<<<dim3(4, 16, 48), 256, 0, stream>>>(xh, wh1, b1, y1h);
    conv2_mfma<<<dim3(4, 8, 48), 256, 0, stream>>>(y1h, wh2, b2, y2h);
    conv3_fused<<<dim3(8, 16, 48), 256, 0, stream>>>(y2h, wh3, b3, out);
}

// Round 7
// 721.030 us; speedup vs baseline: 1.1237x; 1.0705x over previous
//
#include <hip/hip_runtime.h>

// Pipeline: conv3x3(64->128)+ReLU -> conv3x3(128->32)+ReLU -> bilinear x2 -> conv3x3(32->1)
// N=48, H=W=128 input, out [48,1,256,256] fp32.
//
// Round 11: conv2 memory-system fix (first round with conv2 counters).
//  R10 counters: conv2 211us, FETCH 377MB (ideal ~230: quarter-stage reads 64B of each
//  256B pixel, L2 evicts between quarters -> 1.64x over-fetch), LDS bank conflicts
//  5.4M/dispatch (pitch-40 doesn't tile banks under b128), MfmaUtil 11%.
//  Fix 1: y1h split into channel-quarter planes [n][4][128][128][32]. conv1 writes to
//    plane q=wco*2+mf (64B pixel stride, better combining); conv2 stages dense
//    contiguous 16B/lane streams -> FETCH ~240MB.
//  Fix 2: conv2 LDS -> [4][19][34][8] quad-plane (row padded 18->19): ch-stride
//    2584 dwords = 24 mod 32, col-stride 4 dwords -> every 8-lane group of stage
//    ds_write_b128 AND B ds_read_b128 tiles all 32 banks (conv1's property).
//    Same logical mapping -> bit-identical math. LDS 49->41KB.
//  conv1 core / conv3 / repacks unchanged (conv1 = R8 verified 194us).
// Workspace: [A: xh 96MB][B: y1h 192MB split-plane][C: y2h 48MB][W].

typedef _Float16 half_t;
typedef _Float16 half2_t __attribute__((ext_vector_type(2)));
typedef _Float16 half4_t __attribute__((ext_vector_type(4)));
typedef _Float16 half8   __attribute__((ext_vector_type(8)));
typedef float    floatx4  __attribute__((ext_vector_type(4)));
typedef float    floatx16 __attribute__((ext_vector_type(16)));

// ---------- pre-pass: weights fp32 [co][ci][3][3] -> fp16 [tap][co][ci] ----------
__global__ __launch_bounds__(256) void repack_w(
    const float* __restrict__ W1, const float* __restrict__ W2,
    const float* __restrict__ W3, half_t* __restrict__ wh1,
    half_t* __restrict__ wh2, half_t* __restrict__ wh3)
{
    int idx = blockIdx.x * 256 + threadIdx.x;
    if (idx < 73728) {                       // wh1[tap][128][64]
        int ci = idx & 63, co = (idx >> 6) & 127, tap = idx >> 13;
        wh1[idx] = (half_t)W1[(co * 64 + ci) * 9 + tap];
    } else if (idx < 110592) {               // wh2[tap][32][128]
        int j = idx - 73728;
        int ci = j & 127, co = (j >> 7) & 31, tap = j >> 12;
        wh2[j] = (half_t)W2[(co * 128 + ci) * 9 + tap];
    } else if (idx < 110880) {               // wh3[tap][32]
        int j = idx - 110592;
        int ci = j & 31, tap = j >> 5;
        wh3[j] = (half_t)W3[ci * 9 + tap];
    }
}

// ---------- pre-pass: x fp32 [48][64][128][128] -> xh fp16 NHWC [48][128][128][64] ----------
__global__ __launch_bounds__(256) void repack_x(
    const float* __restrict__ x, half_t* __restrict__ xh)
{
    const int tid = threadIdx.x;
    const int px = tid & 127, rr = tid >> 7;
    const int y = blockIdx.x * 2 + rr;
    const int n = blockIdx.y;
    const float* xn = x + (size_t)n * 64 * 16384 + (size_t)y * 128 + px;
    half2_t hb[32];
#pragma unroll
    for (int c2 = 0; c2 < 32; ++c2) {
        float f0 = xn[(size_t)(2 * c2) * 16384];
        float f1 = xn[(size_t)(2 * c2 + 1) * 16384];
        half2_t h; h.x = (half_t)f0; h.y = (half_t)f1;
        hb[c2] = h;
    }
    half_t* op = xh + (((size_t)n * 128 + y) * 128 + px) * 64;
#pragma unroll
    for (int k = 0; k < 8; ++k)
        *(half8*)(op + k * 8) = *(half8*)(&hb[k * 4]);
}

// ---------- conv1: 64->128, relu, 32x32x16 MFMA (R8 core: 194us) ----------
// grid (4, 16, 48). block = 128co x (32w x 8h). 4 waves = (wco 0..1) x (wpx 0..1).
// wave = 64co x (32w x 4h) -> acc[2][4] floatx16 (128 AGPR), 8 MFMA per 6 loads.
// Stage: load-all-then-write. Writeout: y1h channel-quarter planes [n][4][16384][32].
__global__ __launch_bounds__(256, 2) void conv1_mfma(
    const half_t* __restrict__ xh,   // [n][128][128][64]
    const half_t* __restrict__ wh,   // [9][128][64]
    const float*  __restrict__ bias, // [128]
    half_t* __restrict__ y1h)        // [n][4][128][128][32]
{
    __shared__ half_t lx[10 * 34 * 72];   // rows(8+2) x cols(32+2) x ci(64 pad 72)
    const int tid  = threadIdx.x;
    const int lane = tid & 63;
    const int wave = tid >> 6;
    const int l31 = lane & 31, lq = lane >> 5;
    const int wco = wave >> 1, wpx = wave & 1;
    const int x0 = blockIdx.x * 32, y0 = blockIdx.y * 8;
    const int n = blockIdx.z;
    const half_t* xn = xh + (size_t)n * (128 * 128 * 64);

    // stage x tile rows y0-1..y0+8, cols x0-1..x0+32 (zero pad at borders).
    half8 st[11];
#pragma unroll
    for (int k = 0; k < 11; ++k) {
        int idx = tid + k * 256;
        half8 v = {};
        if (idx < 10 * 34 * 8) {
            int ch = idx & 7;
            int p  = idx >> 3;
            int col = p % 34, row = p / 34;
            int gx = x0 - 1 + col, gy = y0 - 1 + row;
            if ((unsigned)gx < 128u && (unsigned)gy < 128u)
                v = *(const half8*)(xn + ((size_t)gy * 128 + gx) * 64 + ch * 8);
        }
        st[k] = v;
    }
#pragma unroll
    for (int k = 0; k < 11; ++k) {
        int idx = tid + k * 256;
        if (idx < 10 * 34 * 8) {
            int ch = idx & 7;
            int p  = idx >> 3;
            int col = p % 34, row = p / 34;
            *(half8*)(&lx[(row * 34 + col) * 72 + ch * 8]) = st[k];
        }
    }
    __syncthreads();

    floatx16 acc[2][4] = {};

#pragma unroll
    for (int tap = 0; tap < 9; ++tap) {
        const int dy = tap / 3, dx = tap % 3;   // compile-time under unroll
        // A: lane holds W[co = wco*64 + mf*32 + l31][k = kc*16 + lq*8 + j]
        const half_t* wt = wh + tap * (128 * 64) + (wco * 64 + l31) * 64 + lq * 8;
        // B: lane holds X[k][px]; wave rows wpx*4+nf, col l31 (+halo shift dx,dy)
        const half_t* bp = &lx[((wpx * 4 + dy) * 34 + l31 + dx) * 72 + lq * 8];
#pragma unroll
        for (int kc = 0; kc < 4; ++kc) {
            half8 a0 = *(const half8*)(wt + kc * 16);
            half8 a1 = *(const half8*)(wt + 32 * 64 + kc * 16);
            half8 b[4];
#pragma unroll
            for (int nf = 0; nf < 4; ++nf)
                b[nf] = *(const half8*)(bp + nf * (34 * 72) + kc * 16);
#pragma unroll
            for (int nf = 0; nf < 4; ++nf) {
                acc[0][nf] = __builtin_amdgcn_mfma_f32_32x32x16_f16(a0, b[nf], acc[0][nf], 0, 0, 0);
                acc[1][nf] = __builtin_amdgcn_mfma_f32_32x32x16_f16(a1, b[nf], acc[1][nf], 0, 0, 0);
            }
        }
    }

    // C/D 32x32: col(px) = l31, row(co local) = (reg&3) + 8*(reg>>2) + 4*lq
    // store to channel-quarter plane q = wco*2 + mf, local channel lq*4 (+8g)
#pragma unroll
    for (int mf = 0; mf < 2; ++mf) {
        int co0 = wco * 64 + mf * 32 + lq * 4;          // global co (for bias)
        int q = wco * 2 + mf;
#pragma unroll
        for (int nf = 0; nf < 4; ++nf) {
            floatx16 A = acc[mf][nf];
            int oy = y0 + wpx * 4 + nf, ox = x0 + l31;
            half_t* op = y1h + ((((size_t)n * 4 + q) * 16384) + oy * 128 + ox) * 32 + lq * 4;
#pragma unroll
            for (int g = 0; g < 4; ++g) {
                floatx4 bv = *(const floatx4*)(bias + co0 + 8 * g);
                half4_t o;
                o.x = (half_t)fmaxf(A[4 * g + 0] + bv.x, 0.f);
                o.y = (half_t)fmaxf(A[4 * g + 1] + bv.y, 0.f);
                o.z = (half_t)fmaxf(A[4 * g + 2] + bv.z, 0.f);
                o.w = (half_t)fmaxf(A[4 * g + 3] + bv.w, 0.f);
                *(half4_t*)(op + 8 * g) = o;
            }
        }
    }
}

// ---------- conv2: 128->32, relu, 16x16x32 MFMA ----------
// grid (4, 8, 48). block = 32co x (32w x 16h px). 4 waves = 4 row-quads.
// ci staged in quarters of 32 from split-plane y1h (dense streams).
// LDS [4 ch-chunks][19 rows pad][34 cols][8 halfs]: ch-stride 2584 dw = 24 mod 32,
// col-stride 4 dw -> stage writes AND B reads tile all 32 banks per 8-lane group.
// wave = 32co x 128px: acc[2][8] floatx4 (64 AGPR).
__global__ __launch_bounds__(256, 3) void conv2_mfma(
    const half_t* __restrict__ y1h,  // [n][4][128][128][32]
    const half_t* __restrict__ wh,   // [9][32][128]
    const float*  __restrict__ bias, // [32]
    half_t* __restrict__ y2h)        // [n][128][128][32]
{
    __shared__ half_t lx[4][19][34][8];   // 41344 B
    const int tid  = threadIdx.x;
    const int lane = tid & 63;
    const int w    = tid >> 6;
    const int l15 = lane & 15, quad = lane >> 4;
    const int x0 = blockIdx.x * 32, y0 = blockIdx.y * 16;
    const int n = blockIdx.z;

    floatx4 acc[2][8] = {};

    for (int h = 0; h < 4; ++h) {        // ci quarters of 32
        const half_t* yn = y1h + ((size_t)n * 4 + h) * (16384 * 32);
        // phase 1: all loads in flight (16B/lane contiguous from dense plane)
        half8 st[10];
#pragma unroll
        for (int k = 0; k < 10; ++k) {
            int idx = tid + k * 256;
            half8 v = {};
            if (idx < 18 * 34 * 4) {
                int ch = idx & 3;
                int p  = idx >> 2;
                int col = p % 34, row = p / 34;
                int gx = x0 - 1 + col, gy = y0 - 1 + row;
                if ((unsigned)gx < 128u && (unsigned)gy < 128u)
                    v = *(const half8*)(yn + ((size_t)gy * 128 + gx) * 32 + ch * 8);
            }
            st[k] = v;
        }
        // phase 2: LDS writes (bank-tiled)
#pragma unroll
        for (int k = 0; k < 10; ++k) {
            int idx = tid + k * 256;
            if (idx < 18 * 34 * 4) {
                int ch = idx & 3;
                int p  = idx >> 2;
                int col = p % 34, row = p / 34;
                *(half8*)(&lx[ch][row][col][0]) = st[k];
            }
        }
        __syncthreads();
#pragma unroll
        for (int tap = 0; tap < 9; ++tap) {
            const int dy = tap / 3, dx = tap % 3;
            // A: co = mf*16 + l15, k = h*32 + quad*8 + j
            const half_t* wt = wh + tap * (32 * 128) + l15 * 128 + h * 32 + quad * 8;
            half8 a0 = *(const half8*)(wt);
            half8 a1 = *(const half8*)(wt + 16 * 128);
#pragma unroll
            for (int nf = 0; nf < 8; ++nf) {
                int rr = w * 4 + (nf >> 1) + dy;          // row in lx
                int cc = (nf & 1) * 16 + l15 + dx;        // col in lx
                half8 b = *(const half8*)(&lx[quad][rr][cc][0]);
                acc[0][nf] = __builtin_amdgcn_mfma_f32_16x16x32_f16(a0, b, acc[0][nf], 0, 0, 0);
                acc[1][nf] = __builtin_amdgcn_mfma_f32_16x16x32_f16(a1, b, acc[1][nf], 0, 0, 0);
            }
        }
        __syncthreads();
    }

    // C/D 16x16: col(px)=l15, row(co local)=quad*4+reg
#pragma unroll
    for (int mf = 0; mf < 2; ++mf) {
        int co0 = mf * 16 + quad * 4;
        floatx4 bv = *(const floatx4*)(bias + co0);
#pragma unroll
        for (int nf = 0; nf < 8; ++nf) {
            int oy = y0 + w * 4 + (nf >> 1), ox = x0 + (nf & 1) * 16 + l15;
            floatx4 A = acc[mf][nf];
            half4_t o;
            o.x = (half_t)fmaxf(A.x + bv.x, 0.f);
            o.y = (half_t)fmaxf(A.y + bv.y, 0.f);
            o.z = (half_t)fmaxf(A.z + bv.z, 0.f);
            o.w = (half_t)fmaxf(A.w + bv.w, 0.f);
            *(half4_t*)(y2h + (((size_t)n * 128 + oy) * 128 + ox) * 32 + co0) = o;
        }
    }
}

// ---------- conv3 fused with bilinear x2: 32->1, fp32 out ----------
// grid (8, 16, 48): block = 32w x 16h out px (2 sub-tiles), thread = 2 px.
// 18x34x32 upsampled halo tile built in LDS from y2h (bilinear, clamp edge;
// zero outside image for conv pad). 2x per-block work amortizes stage cost.
__global__ __launch_bounds__(256) void conv3_fused(
    const half_t* __restrict__ y2h,  // [n][128][128][32]
    const half_t* __restrict__ wh3,  // [9][32]
    const float*  __restrict__ bias, // [1]
    float* __restrict__ out)         // [n][256][256]
{
    __shared__ half_t lu[18 * 34 * 40];   // rows(16+2) x cols(32+2) x ci(32 pad 40)
    const int tid = threadIdx.x;
    const int c = tid & 31, r = tid >> 5;
    const int x0 = blockIdx.x * 32, y0 = blockIdx.y * 16;
    const int n = blockIdx.z;
    const half_t* base = y2h + (size_t)n * (128 * 128 * 32);

    // stage upsampled tile rows Y = y0-1 .. y0+16 (18 rows) x 34 cols x 32 ci.
    half8 st[10];
#pragma unroll
    for (int k = 0; k < 10; ++k) {
        int idx = tid + k * 256;
        half8 o = {};
        if (idx < 18 * 34 * 4) {
            int cc = idx & 3;
            int p  = idx >> 2;
            int col = p % 34, row = p / 34;
            int X = x0 - 1 + col, Y = y0 - 1 + row;
            if ((unsigned)X < 256u && (unsigned)Y < 256u) {
                int jx = X >> 1, jy = Y >> 1;
                int jxo = (X & 1) ? (jx < 127 ? jx + 1 : 127) : (jx > 0 ? jx - 1 : 0);
                int jyo = (Y & 1) ? (jy < 127 ? jy + 1 : 127) : (jy > 0 ? jy - 1 : 0);
                const half_t* p00 = base + ((size_t)jy  * 128 + jx ) * 32 + cc * 8;
                const half_t* p01 = base + ((size_t)jy  * 128 + jxo) * 32 + cc * 8;
                const half_t* p10 = base + ((size_t)jyo * 128 + jx ) * 32 + cc * 8;
                const half_t* p11 = base + ((size_t)jyo * 128 + jxo) * 32 + cc * 8;
                half8 v00 = *(const half8*)p00;
                half8 v01 = *(const half8*)p01;
                half8 v10 = *(const half8*)p10;
                half8 v11 = *(const half8*)p11;
                o = v00 * (half_t)0.5625f + (v01 + v10) * (half_t)0.1875f
                  + v11 * (half_t)0.0625f;
            }
        }
        st[k] = o;
    }
#pragma unroll
    for (int k = 0; k < 10; ++k) {
        int idx = tid + k * 256;
        if (idx < 18 * 34 * 4) {
            int cc = idx & 3;
            int p  = idx >> 2;
            int col = p % 34, row = p / 34;
            *(half8*)(&lu[(row * 34 + col) * 40 + cc * 8]) = st[k];
        }
    }
    __syncthreads();

#pragma unroll
    for (int s = 0; s < 2; ++s) {        // two 8-row sub-tiles
        float acc = 0.f;
#pragma unroll
        for (int tap = 0; tap < 9; ++tap) {
            const int dy = tap / 3, dx = tap % 3;
            const half_t* lp = &lu[((s * 8 + r + dy) * 34 + c + dx) * 40];
            const half_t* wp = wh3 + tap * 32;
#pragma unroll
            for (int cc = 0; cc < 4; ++cc) {
                half8 v = *(const half8*)(lp + cc * 8);
                half8 w = *(const half8*)(wp + cc * 8);
                acc = __builtin_amdgcn_fdot2(__builtin_shufflevector(v, v, 0, 1),
                                             __builtin_shufflevector(w, w, 0, 1), acc, false);
                acc = __builtin_amdgcn_fdot2(__builtin_shufflevector(v, v, 2, 3),
                                             __builtin_shufflevector(w, w, 2, 3), acc, false);
                acc = __builtin_amdgcn_fdot2(__builtin_shufflevector(v, v, 4, 5),
                                             __builtin_shufflevector(w, w, 4, 5), acc, false);
                acc = __builtin_amdgcn_fdot2(__builtin_shufflevector(v, v, 6, 7),
                                             __builtin_shufflevector(w, w, 6, 7), acc, false);
            }
        }
        out[((size_t)n * 256 + (y0 + s * 8 + r)) * 256 + x0 + c] = acc + bias[0];
    }
}

extern "C" void kernel_launch(void* const* d_in, const int* in_sizes, int n_in,
                              void* d_out, int out_size, void* d_ws, size_t ws_size,
                              hipStream_t stream) {
    const float* x  = (const float*)d_in[0];
    // d_in[1] = to_process (identity arange), d_in[2] = batch_size: unused.
    const float* W1 = (const float*)d_in[3];
    const float* b1 = (const float*)d_in[4];
    const float* W2 = (const float*)d_in[5];
    const float* b2 = (const float*)d_in[6];
    const float* W3 = (const float*)d_in[7];
    const float* b3 = (const float*)d_in[8];
    float* out = (float*)d_out;

    char* ws = (char*)d_ws;
    half_t* xh  = (half_t*)ws;                   // 96 MB, region A
    half_t* y1h = (half_t*)(ws + 201326592ull);  // 192 MB, region B (split planes)
    half_t* y2h = (half_t*)(ws + 402653184ull);  // 48 MB,  region C
    half_t* wh1 = (half_t*)(ws + 452984832ull);  // 9*128*64
    half_t* wh2 = wh1 + 73728;                   // 9*32*128
    half_t* wh3 = wh2 + 36864;                   // 9*32

    repack_w<<<434, 256, 0, stream>>>(W1, W2, W3, wh1, wh2, wh3);
    repack_x<<<dim3(64, 48), 256, 0, stream>>>(x, xh);
    conv1_mfma<<<dim3(4, 16, 48), 256, 0, stream>>>(xh, wh1, b1, y1h);
    conv2_mfma<<<dim3(4, 8, 48), 256, 0, stream>>>(y1h, wh2, b2, y2h);
    conv3_fused<<<dim3(8, 16, 48), 256, 0, stream>>>(y2h, wh3, b3, out);
}